// Round 1
// baseline (28225.290 us; speedup 1.0000x reference)
//
#include <hip/hip_runtime.h>

// Shapes (fixed for this problem)
#define B   32
#define T   64
#define D   512
#define H   512     // encoder hidden per direction
#define H2  1024    // 2*H, decoder hidden
#define G4  4096    // 4*H2
#define V   2048
#define DEC_IN 2560 // E + 2*H2

// ---------------- helpers ----------------
__device__ __forceinline__ float sigm(float x) { return 1.f / (1.f + expf(-x)); }

// monotonic float->uint encode (for argmax via integer max)
__device__ __forceinline__ unsigned fenc(float f) {
  unsigned u = __float_as_uint(f);
  return (u & 0x80000000u) ? ~u : (u | 0x80000000u);
}

// device-scope grid barrier over `target` blocks; each counter slot used once.
__device__ __forceinline__ void gbar(unsigned* ctr, unsigned target) {
  __syncthreads();
  if (threadIdx.x == 0) {
    __hip_atomic_fetch_add(ctr, 1u, __ATOMIC_ACQ_REL, __HIP_MEMORY_SCOPE_AGENT);
    while (__hip_atomic_load(ctr, __ATOMIC_ACQUIRE, __HIP_MEMORY_SCOPE_AGENT) < target)
      __builtin_amdgcn_s_sleep(8);
  }
  __syncthreads();
}

// ---------------- generic fp32 GEMM:  C[m,n] = sum_k A[m,k]*W[n,k] + bias0[n] + bias1[n]
// grid = (N/64, M/128), block = 256.  BM=128, BN=64, BK=16, 8x4 per thread.
__global__ __launch_bounds__(256) void gemm_nt(
    const float* __restrict__ A, int lda,
    const float* __restrict__ W, int ldw,
    float* __restrict__ C, int ldc,
    const float* __restrict__ bias0, const float* __restrict__ bias1,
    int K)
{
  __shared__ float As[16][132];
  __shared__ float Ws[16][68];
  const int tid = threadIdx.x;
  const int nb = blockIdx.x * 64;
  const int mb = blockIdx.y * 128;
  const int tx = tid & 15;   // n:  tx*4
  const int ty = tid >> 4;   // m:  ty*8
  float acc[8][4] = {};

  const int am = tid >> 1, ak = (tid & 1) * 8;
  const int wn = tid >> 2, wk = (tid & 3) * 4;
  const float* aptr = A + (size_t)(mb + am) * lda + ak;
  const float* wptr = W + (size_t)(nb + wn) * ldw + wk;

  for (int k0 = 0; k0 < K; k0 += 16) {
    float4 u = *(const float4*)(aptr + k0);
    float4 v = *(const float4*)(aptr + k0 + 4);
    float4 w = *(const float4*)(wptr + k0);
    As[ak+0][am] = u.x; As[ak+1][am] = u.y; As[ak+2][am] = u.z; As[ak+3][am] = u.w;
    As[ak+4][am] = v.x; As[ak+5][am] = v.y; As[ak+6][am] = v.z; As[ak+7][am] = v.w;
    Ws[wk+0][wn] = w.x; Ws[wk+1][wn] = w.y; Ws[wk+2][wn] = w.z; Ws[wk+3][wn] = w.w;
    __syncthreads();
    #pragma unroll
    for (int k = 0; k < 16; ++k) {
      float4 a0 = *(const float4*)&As[k][ty*8];
      float4 a1 = *(const float4*)&As[k][ty*8+4];
      float4 wv = *(const float4*)&Ws[k][tx*4];
      float av[8] = {a0.x,a0.y,a0.z,a0.w,a1.x,a1.y,a1.z,a1.w};
      #pragma unroll
      for (int i = 0; i < 8; ++i) {
        acc[i][0] += av[i]*wv.x; acc[i][1] += av[i]*wv.y;
        acc[i][2] += av[i]*wv.z; acc[i][3] += av[i]*wv.w;
      }
    }
    __syncthreads();
  }
  float b4[4];
  #pragma unroll
  for (int j = 0; j < 4; ++j) {
    float bv = 0.f;
    if (bias0) bv += bias0[nb + tx*4 + j];
    if (bias1) bv += bias1[nb + tx*4 + j];
    b4[j] = bv;
  }
  #pragma unroll
  for (int i = 0; i < 8; ++i) {
    float4 o;
    o.x = acc[i][0] + b4[0]; o.y = acc[i][1] + b4[1];
    o.z = acc[i][2] + b4[2]; o.w = acc[i][3] + b4[3];
    *(float4*)&C[(size_t)(mb + ty*8 + i) * ldc + nb + tx*4] = o;
  }
}

// ---------------- bidirectional encoder LSTM scan (persistent, 256 blocks) --------------
// blocks 0..127: forward dir; 128..255: backward. Per dir: 4 b-tiles(8) x 32 hi-tiles(16).
// Cell state c lives in registers (block owns fixed (b,hi) set). 1 grid barrier/step/dir.
__global__ __launch_bounds__(256) void encoder_scan(
    const float* __restrict__ xg_f, const float* __restrict__ xg_b,
    const float* __restrict__ Whh_f, const float* __restrict__ Whh_b,
    const int* __restrict__ mask,
    float* __restrict__ henc, float* __restrict__ output,
    unsigned* __restrict__ ebar)
{
  __shared__ float hs[8][516];   // 8 b x 512 h, padded stride (bank-safe)
  __shared__ float gl[512];      // gates for this block's cells
  const int blk = blockIdx.x, tid = threadIdx.x;
  const int dir   = blk >> 7;
  const int blkd  = blk & 127;
  const int btile = blkd >> 5;    // 0..3
  const int hitile= blkd & 31;    // 0..31
  const float* xg  = dir ? xg_b : xg_f;
  const float* Whh = dir ? Whh_b : Whh_f;
  float* hbuf = henc + dir * (B*H);
  unsigned* bc = ebar + dir * 64;

  const int g0  = tid >> 7;          // gate 0/1 (second output is gate+2)
  const int rem = tid & 127;
  const int ob  = rem >> 4, ohi = rem & 15;
  const int b_o = btile*8 + ob;
  const int j1  = g0*512 + hitile*16 + ohi;
  const int j2  = (g0+2)*512 + hitile*16 + ohi;
  const float4* w1v = (const float4*)(Whh + (size_t)j1*512);
  const float4* w2v = (const float4*)(Whh + (size_t)j2*512);
  const float4* hv  = (const float4*)&hs[ob][0];

  float c_reg = 0.f;

  for (int tt = 0; tt < 64; ++tt) {
    const int t = dir ? (63 - tt) : tt;
    {  // stage h (8 b x 512), coalesced fl4, stride-1 LDS
      const float* sb = hbuf + btile*(8*H);
      #pragma unroll
      for (int q = 0; q < 4; ++q) {
        int f = q*1024 + tid*4;
        *(float4*)&hs[f >> 9][f & 511] = *(const float4*)&sb[f];
      }
    }
    __syncthreads();
    float acc1 = xg[(size_t)(b_o*T + t)*2048 + j1];   // bih+bhh folded in
    float acc2 = xg[(size_t)(b_o*T + t)*2048 + j2];
    #pragma unroll 8
    for (int k4 = 0; k4 < 128; ++k4) {
      float4 h4 = hv[k4];
      float4 u = w1v[k4], v = w2v[k4];
      acc1 += h4.x*u.x + h4.y*u.y + h4.z*u.z + h4.w*u.w;
      acc2 += h4.x*v.x + h4.y*v.y + h4.z*v.z + h4.w*v.w;
    }
    gl[g0*128 + rem]     = acc1;
    gl[(g0+2)*128 + rem] = acc2;
    __syncthreads();
    if (tid < 128) {  // LSTM cell for this block's 8b x 16hi
      float gi = gl[tid], gf = gl[128+tid], gg = gl[256+tid], go = gl[384+tid];
      c_reg = sigm(gf)*c_reg + sigm(gi)*tanhf(gg);
      float h = sigm(go)*tanhf(c_reg);
      int cb = tid >> 4, chi = tid & 15;
      int b = btile*8 + cb, hi = hitile*16 + chi;
      hbuf[b*H + hi] = h;
      output[(size_t)(b*T + t)*H2 + dir*H + hi] = h * (float)mask[b*T + t];
    }
    gbar(bc + tt, 128);
  }
}

// ---------------- decoder attention helper (one block handles one batch row b) ----------
// sc[t] = <hvec, proj[b,t,:]> ; p = softmax(sc)*mask ; dst = sum_t p[t]*output[b,t,:]
__device__ void attend_ctx(int b, const float* __restrict__ hvec, float* __restrict__ dst,
                           const float* __restrict__ output, const float* __restrict__ projo,
                           const int* __restrict__ mask, float* scp, float* sc, int tid)
{
  const int tq = tid >> 2, dq = tid & 3;
  const float4* hv = (const float4*)(hvec + dq*256);
  const float4* pv = (const float4*)(projo + (size_t)(b*T + tq)*H2 + dq*256);
  float p = 0.f;
  #pragma unroll 8
  for (int k4 = 0; k4 < 64; ++k4) {
    float4 a = hv[k4], q = pv[k4];
    p += a.x*q.x + a.y*q.y + a.z*q.z + a.w*q.w;
  }
  scp[tid] = p;
  __syncthreads();
  if (tid < 64) sc[tid] = scp[tid*4] + scp[tid*4+1] + scp[tid*4+2] + scp[tid*4+3];
  __syncthreads();
  if (tid == 0) {
    float mx = sc[0];
    for (int i = 1; i < 64; ++i) mx = fmaxf(mx, sc[i]);
    float sum = 0.f;
    for (int i = 0; i < 64; ++i) { float e = expf(sc[i] - mx); sc[i] = e; sum += e; }
    float inv = 1.f / sum;
    for (int i = 0; i < 64; ++i) sc[i] *= inv * (float)mask[b*T + i];
  }
  __syncthreads();
  float a0=0,a1=0,a2=0,a3=0;
  for (int tt = 0; tt < 64; ++tt) {
    float pp = sc[tt];
    const float* orow = output + (size_t)(b*T + tt)*H2 + tid;
    a0 += pp*orow[0]; a1 += pp*orow[256]; a2 += pp*orow[512]; a3 += pp*orow[768];
  }
  dst[tid] = a0; dst[tid+256] = a1; dst[tid+512] = a2; dst[tid+768] = a3;
}

// ---------------- persistent decoder (256 blocks, 2 grid barriers / step) ----------------
__global__ __launch_bounds__(256) void decoder_kernel(
    const float* __restrict__ basep, const float* __restrict__ tagp,
    const float* __restrict__ dWhh,  const float* __restrict__ dWih,
    const float* __restrict__ Wout,  const float* __restrict__ bout,
    const float* __restrict__ projo, const float* __restrict__ output,
    const int* __restrict__ mask,
    float* __restrict__ hdec, float* __restrict__ ctx,
    unsigned long long* __restrict__ argslot,
    unsigned* __restrict__ dbar,
    float* __restrict__ out)
{
  __shared__ float smem[8*1028 + 512];         // hc staging + gates (35 KB)
  float (*hcs)[1028] = (float (*)[1028])smem;
  float* gl = smem + 8*1028;

  const int blk = blockIdx.x, tid = threadIdx.x;
  const int btile = blk >> 6, hitile = blk & 63;
  const int bb = btile * 8;

  // P1 mapping: 512 outputs/block = 16hi x 4gates x 8b ; 2 per thread (gates g, g+2)
  const int g0  = tid >> 7;
  const int rem = tid & 127;
  const int ob  = rem >> 4, ohi = rem & 15;
  const int b_o = bb + ob;
  const int j1  = g0*H2 + hitile*16 + ohi;
  const int j2  = (g0+2)*H2 + hitile*16 + ohi;

  // P3 mapping: 32v x 8b per block, K split 4 ways
  const int vbase = (blk & 63) * 32;
  const int kq  = tid >> 6;
  const int vg  = (tid >> 3) & 7;
  const int bl3 = tid & 7;

  float c_reg = 0.f;   // decoder cell state, register-resident all 64 steps
  int bslot = 0;

  // ---- prologue: context0 = attend(last_output) ----
  if (blk < B) {
    const int b = blk;
    int len = -1;
    for (int i = 0; i < T; ++i) len += mask[b*T + i];
    attend_ctx(b, output + (size_t)(b*T + len)*H2, ctx + b*H2,
               output, projo, mask, smem, smem + 256, tid);
  }
  gbar(dbar + bslot++, 256);

  for (int t = 0; t < T; ++t) {
    const int cur = t & 1, nxt = cur ^ 1;

    // ---- P1: gates = base[t] + tag_proj[last_tag] + [h;ctx] @ [Whh | Wih_ctx]^T ----
    float acc1 = basep[(size_t)(b_o*T + t)*G4 + j1];
    float acc2 = basep[(size_t)(b_o*T + t)*G4 + j2];
    if (t > 0) {
      unsigned long long s = argslot[((t+2)%3)*B + b_o];   // slot written step t-1
      unsigned tag = ~(unsigned)s;
      acc1 += tagp[(size_t)tag*G4 + j1];
      acc2 += tagp[(size_t)tag*G4 + j2];
    }
    for (int c = 0; c < 2; ++c) {   // c=0: h (K 0..1023 via dWhh); c=1: ctx (via dWih ctx cols)
      if (c) __syncthreads();
      const float* sb = (c == 0) ? (hdec + bb*H2) : (ctx + cur*(B*H2) + bb*H2);
      #pragma unroll
      for (int q = 0; q < 8; ++q)
        *(float4*)&hcs[q][tid*4] = *(const float4*)&sb[q*H2 + tid*4];
      __syncthreads();
      const float4* w1v = (c == 0) ? (const float4*)(dWhh + (size_t)j1*H2)
                                   : (const float4*)(dWih + (size_t)j1*DEC_IN + 512);
      const float4* w2v = (c == 0) ? (const float4*)(dWhh + (size_t)j2*H2)
                                   : (const float4*)(dWih + (size_t)j2*DEC_IN + 512);
      const float4* hv = (const float4*)&hcs[ob][0];
      #pragma unroll 8
      for (int k4 = 0; k4 < 256; ++k4) {
        float4 h4 = hv[k4];
        float4 u = w1v[k4], v = w2v[k4];
        acc1 += h4.x*u.x + h4.y*u.y + h4.z*u.z + h4.w*u.w;
        acc2 += h4.x*v.x + h4.y*v.y + h4.z*v.z + h4.w*v.w;
      }
    }
    gl[g0*128 + rem]     = acc1;
    gl[(g0+2)*128 + rem] = acc2;
    __syncthreads();

    // ---- P2: LSTM cell (+ argmax slot reset, triple-buffered) ----
    if (tid < 128) {
      float gi = gl[tid], gf = gl[128+tid], gg = gl[256+tid], go = gl[384+tid];
      c_reg = sigm(gf)*c_reg + sigm(gi)*tanhf(gg);
      float h = sigm(go)*tanhf(c_reg);
      int cb = tid >> 4, chi = tid & 15;
      hdec[(size_t)(bb + cb)*H2 + hitile*16 + chi] = h;
    } else if (hitile == 0 && tid < 136) {
      argslot[((t+1)%3)*B + bb + (tid - 128)] = 0ull;
    }
    gbar(dbar + bslot++, 256);

    // ---- P3: score = [h_new ; ctx_old] @ Wout^T + bout ; write out ; argmax atomicMax --
    {
      const int v0 = vbase + vg*4;
      const int b3 = bb + bl3;
      const float* hsrc = (kq < 2) ? (hdec + (size_t)b3*H2 + kq*512)
                                   : (ctx + cur*(B*H2) + (size_t)b3*H2 + (kq-2)*512);
      const float4* hq  = (const float4*)hsrc;
      const float4* wv0 = (const float4*)(Wout + (size_t)(v0+0)*2048 + kq*512);
      const float4* wv1 = (const float4*)(Wout + (size_t)(v0+1)*2048 + kq*512);
      const float4* wv2 = (const float4*)(Wout + (size_t)(v0+2)*2048 + kq*512);
      const float4* wv3 = (const float4*)(Wout + (size_t)(v0+3)*2048 + kq*512);
      float a0=0,a1=0,a2=0,a3=0;
      #pragma unroll 4
      for (int k4 = 0; k4 < 128; ++k4) {
        float4 h4 = hq[k4];
        float4 p0 = wv0[k4], p1 = wv1[k4], p2 = wv2[k4], p3 = wv3[k4];
        a0 += h4.x*p0.x + h4.y*p0.y + h4.z*p0.z + h4.w*p0.w;
        a1 += h4.x*p1.x + h4.y*p1.y + h4.z*p1.z + h4.w*p1.w;
        a2 += h4.x*p2.x + h4.y*p2.y + h4.z*p2.z + h4.w*p2.w;
        a3 += h4.x*p3.x + h4.y*p3.y + h4.z*p3.z + h4.w*p3.w;
      }
      float* part = smem;   // previous smem uses completed before last gbar
      part[kq*256 + bl3*32 + vg*4 + 0] = a0;
      part[kq*256 + bl3*32 + vg*4 + 1] = a1;
      part[kq*256 + bl3*32 + vg*4 + 2] = a2;
      part[kq*256 + bl3*32 + vg*4 + 3] = a3;
      __syncthreads();
      const int vl = tid & 31, bl = tid >> 5;
      float s = part[bl*32 + vl] + part[256 + bl*32 + vl]
              + part[512 + bl*32 + vl] + part[768 + bl*32 + vl]
              + bout[vbase + vl];
      out[(size_t)((bb + bl)*T + t)*V + vbase + vl] = s;
      // argmax: pack (monotone float, ~index) so max => first max index
      unsigned long long e = ((unsigned long long)fenc(s) << 32)
                           | (unsigned long long)(unsigned)(~(unsigned)(vbase + vl));
      #pragma unroll
      for (int dd = 16; dd; dd >>= 1) {
        unsigned long long o2 = __shfl_down(e, (unsigned)dd, 32);
        if (o2 > e) e = o2;
      }
      if (vl == 0) atomicMax(&argslot[(t%3)*B + bb + bl], e);
    }

    // ---- P5: new_context = attend(h_new)  (blocks 0..31, double-buffered ctx) ----
    if (blk < B) {
      __syncthreads();
      attend_ctx(blk, hdec + (size_t)blk*H2, ctx + nxt*(B*H2) + blk*H2,
                 output, projo, mask, smem, smem + 256, tid);
    }
    gbar(dbar + bslot++, 256);
  }
}

// ---------------- host launch ----------------
extern "C" void kernel_launch(void* const* d_in, const int* in_sizes, int n_in,
                              void* d_out, int out_size, void* d_ws, size_t ws_size,
                              hipStream_t stream)
{
  (void)in_sizes; (void)n_in; (void)out_size; (void)ws_size;
  const float* emb    = (const float*)d_in[0];
  const int*   mask   = (const int*)d_in[1];
  const float* Wih_f  = (const float*)d_in[2];
  const float* Whh_f  = (const float*)d_in[3];
  const float* bih_f  = (const float*)d_in[4];
  const float* bhh_f  = (const float*)d_in[5];
  const float* Wih_b  = (const float*)d_in[6];
  const float* Whh_b  = (const float*)d_in[7];
  const float* bih_b  = (const float*)d_in[8];
  const float* bhh_b  = (const float*)d_in[9];
  const float* attnW  = (const float*)d_in[10];
  // d_in[11] = attn_b: scalar added pre-softmax -> shift-invariant, unused
  const float* tagemb = (const float*)d_in[12];
  const float* dWih   = (const float*)d_in[13];
  const float* dWhh   = (const float*)d_in[14];
  const float* dbih   = (const float*)d_in[15];
  const float* dbhh   = (const float*)d_in[16];
  const float* Wout   = (const float*)d_in[17];
  const float* bout   = (const float*)d_in[18];
  float* out = (float*)d_out;

  // workspace layout (floats); total ~118 MB
  float* ws = (float*)d_ws;
  float* xg_f   = ws + 0;          // B*T*2048
  float* xg_b   = ws + 4194304;    // B*T*2048
  float* outbuf = ws + 8388608;    // B*T*H2   (masked encoder output, concat f|b)
  float* projo  = ws + 10485760;   // B*T*H2   (attn_W @ output)
  float* basep  = ws + 12582912;   // B*T*G4   (aligned @ Wih_al^T + dbih + dbhh)
  float* tagp   = ws + 20971520;   // V*G4     (tag_embed @ Wih_emb^T)
  float* henc   = ws + 29360128;   // 2*B*H
  float* hdec   = ws + 29392896;   // B*H2
  float* ctx    = ws + 29425664;   // 2*B*H2 (double-buffered context)
  unsigned long long* argslot = (unsigned long long*)(ws + 29491200);  // 3*B u64
  unsigned* dbar = (unsigned*)(ws + 29491392);   // 512 slots
  unsigned* ebar = dbar + 512;                   // 128 slots

  // zero all persistent-kernel state every call (graph-replay deterministic)
  hipMemsetAsync((void*)(ws + 29360128), 0, (size_t)(29492416 - 29360128) * sizeof(float), stream);

  // encoder input GEMMs: xg = emb @ Wih^T + bih + bhh   (M=2048,N=2048,K=512)
  gemm_nt<<<dim3(32, 16), 256, 0, stream>>>(emb, 512, Wih_f, 512, xg_f, 2048, bih_f, bhh_f, 512);
  gemm_nt<<<dim3(32, 16), 256, 0, stream>>>(emb, 512, Wih_b, 512, xg_b, 2048, bih_b, bhh_b, 512);
  // tag_proj = tag_embed @ dec_Wih[:, :512]^T   (M=2048,N=4096,K=512)
  gemm_nt<<<dim3(64, 16), 256, 0, stream>>>(tagemb, 512, dWih, DEC_IN, tagp, G4, nullptr, nullptr, 512);
  // bidirectional encoder scan
  encoder_scan<<<256, 256, 0, stream>>>(xg_f, xg_b, Whh_f, Whh_b, mask, henc, outbuf, ebar);
  // proj_out[bt,d] = sum_e attn_W[d,e]*output[bt,e]   (M=2048,N=1024,K=1024)
  gemm_nt<<<dim3(16, 16), 256, 0, stream>>>(outbuf, H2, attnW, H2, projo, H2, nullptr, nullptr, H2);
  // base[bt,j] = output[bt,:] @ dec_Wih[:,1536:]^T + dbih + dbhh   (M=2048,N=4096,K=1024)
  gemm_nt<<<dim3(64, 16), 256, 0, stream>>>(outbuf, H2, dWih + 1536, DEC_IN, basep, G4, dbih, dbhh, H2);
  // persistent decoder
  decoder_kernel<<<256, 256, 0, stream>>>(basep, tagp, dWhh, dWih, Wout, bout,
                                          projo, outbuf, mask, hdec, ctx, argslot, dbar, out);
}

// Round 2
// 11107.616 us; speedup vs baseline: 2.5411x; 2.5411x over previous
//
#include <hip/hip_runtime.h>

#define B   32
#define T   64
#define D   512
#define H   512
#define H2  1024
#define G4  4096
#define V   2048
#define DEC_IN 2560

__device__ __forceinline__ float sigm(float x) { return 1.f / (1.f + expf(-x)); }

__device__ __forceinline__ unsigned fenc(float f) {
  unsigned u = __float_as_uint(f);
  return (u & 0x80000000u) ? ~u : (u | 0x80000000u);
}

// device-scope grid barrier over `target` blocks; each counter slot used once.
__device__ __forceinline__ void gbar(unsigned* ctr, unsigned target) {
  __syncthreads();
  if (threadIdx.x == 0) {
    __hip_atomic_fetch_add(ctr, 1u, __ATOMIC_ACQ_REL, __HIP_MEMORY_SCOPE_AGENT);
    while (__hip_atomic_load(ctr, __ATOMIC_ACQUIRE, __HIP_MEMORY_SCOPE_AGENT) < target)
      __builtin_amdgcn_s_sleep(8);
  }
  __syncthreads();
}

// ---------------- generic fp32 GEMM:  C[m,n] = sum_k A[m,k]*W[n,k] + bias0[n] + bias1[n]
__global__ __launch_bounds__(256) void gemm_nt(
    const float* __restrict__ A, int lda,
    const float* __restrict__ W, int ldw,
    float* __restrict__ C, int ldc,
    const float* __restrict__ bias0, const float* __restrict__ bias1,
    int K)
{
  __shared__ float As[16][132];
  __shared__ float Ws[16][68];
  const int tid = threadIdx.x;
  const int nb = blockIdx.x * 64;
  const int mb = blockIdx.y * 128;
  const int tx = tid & 15;
  const int ty = tid >> 4;
  float acc[8][4] = {};

  const int am = tid >> 1, ak = (tid & 1) * 8;
  const int wn = tid >> 2, wk = (tid & 3) * 4;
  const float* aptr = A + (size_t)(mb + am) * lda + ak;
  const float* wptr = W + (size_t)(nb + wn) * ldw + wk;

  for (int k0 = 0; k0 < K; k0 += 16) {
    float4 u = *(const float4*)(aptr + k0);
    float4 v = *(const float4*)(aptr + k0 + 4);
    float4 w = *(const float4*)(wptr + k0);
    As[ak+0][am] = u.x; As[ak+1][am] = u.y; As[ak+2][am] = u.z; As[ak+3][am] = u.w;
    As[ak+4][am] = v.x; As[ak+5][am] = v.y; As[ak+6][am] = v.z; As[ak+7][am] = v.w;
    Ws[wk+0][wn] = w.x; Ws[wk+1][wn] = w.y; Ws[wk+2][wn] = w.z; Ws[wk+3][wn] = w.w;
    __syncthreads();
    #pragma unroll
    for (int k = 0; k < 16; ++k) {
      float4 a0 = *(const float4*)&As[k][ty*8];
      float4 a1 = *(const float4*)&As[k][ty*8+4];
      float4 wv = *(const float4*)&Ws[k][tx*4];
      float av[8] = {a0.x,a0.y,a0.z,a0.w,a1.x,a1.y,a1.z,a1.w};
      #pragma unroll
      for (int i = 0; i < 8; ++i) {
        acc[i][0] += av[i]*wv.x; acc[i][1] += av[i]*wv.y;
        acc[i][2] += av[i]*wv.z; acc[i][3] += av[i]*wv.w;
      }
    }
    __syncthreads();
  }
  float b4[4];
  #pragma unroll
  for (int j = 0; j < 4; ++j) {
    float bv = 0.f;
    if (bias0) bv += bias0[nb + tx*4 + j];
    if (bias1) bv += bias1[nb + tx*4 + j];
    b4[j] = bv;
  }
  #pragma unroll
  for (int i = 0; i < 8; ++i) {
    float4 o;
    o.x = acc[i][0] + b4[0]; o.y = acc[i][1] + b4[1];
    o.z = acc[i][2] + b4[2]; o.w = acc[i][3] + b4[3];
    *(float4*)&C[(size_t)(mb + ty*8 + i) * ldc + nb + tx*4] = o;
  }
}

// ---------------- attention helper: block handles batch row b; writes ctx transposed ----
// scratch needs 320 floats.
__device__ void attend_t(int b, const float* __restrict__ hvec, float* __restrict__ ctxdst,
                         const float* __restrict__ outbuf, const float* __restrict__ projo,
                         const int* __restrict__ mask, float* scratch, int tid)
{
  float* scp = scratch;        // 256
  float* scv = scratch + 256;  // 64
  const int tq = tid >> 2, dq = tid & 3;
  const float4* hv = (const float4*)(hvec + dq*256);
  const float4* pv = (const float4*)(projo + (size_t)(b*T + tq)*H2 + dq*256);
  float p = 0.f;
  #pragma unroll 8
  for (int k4 = 0; k4 < 64; ++k4) {
    float4 a = hv[k4], q = pv[k4];
    p += a.x*q.x + a.y*q.y + a.z*q.z + a.w*q.w;
  }
  scp[tid] = p;
  __syncthreads();
  if (tid < 64) scv[tid] = scp[tid*4] + scp[tid*4+1] + scp[tid*4+2] + scp[tid*4+3];
  __syncthreads();
  if (tid == 0) {
    float mx = scv[0];
    for (int i = 1; i < 64; ++i) mx = fmaxf(mx, scv[i]);
    float sum = 0.f;
    for (int i = 0; i < 64; ++i) { float e = expf(scv[i] - mx); scv[i] = e; sum += e; }
    float inv = 1.f / sum;
    for (int i = 0; i < 64; ++i) scv[i] *= inv * (float)mask[b*T + i];
  }
  __syncthreads();
  float a0 = 0, a1 = 0, a2 = 0, a3 = 0;
  for (int tt = 0; tt < 64; ++tt) {
    float pp = scv[tt];
    float4 o4 = *(const float4*)(outbuf + (size_t)(b*T + tt)*H2 + tid*4);
    a0 += pp*o4.x; a1 += pp*o4.y; a2 += pp*o4.z; a3 += pp*o4.w;
  }
  int k0 = tid*4;
  ctxdst[(k0+0)*32 + b] = a0;
  ctxdst[(k0+1)*32 + b] = a1;
  ctxdst[(k0+2)*32 + b] = a2;
  ctxdst[(k0+3)*32 + b] = a3;
}

// ---------------- persistent encoder: weights in registers, 1 barrier/step/dir --------
// 256 blocks: dir = blk>>7; block owns 4 hidden units (16 gate rows of Whh).
__global__ __launch_bounds__(256, 1) void encoder_persistent(
    const float* __restrict__ xg_f, const float* __restrict__ xg_b,
    const float* __restrict__ Whh_f, const float* __restrict__ Whh_b,
    const int* __restrict__ mask,
    float* __restrict__ hencT,    // [dir][2][512][32]
    float* __restrict__ outbuf,
    unsigned* __restrict__ ebar)
{
  __shared__ float S_lds[2][128*36];
  __shared__ float pacc[2048];
  __shared__ float g_lds[512];
  const int blk = blockIdx.x, tid = threadIdx.x;
  const int lane = tid & 63, wv = tid >> 6;
  const int dir = blk >> 7, nd = blk & 127;
  const int hibase = nd * 4;
  const int jj = tid & 7, kk = tid >> 3;
  const float* xg  = dir ? xg_b : xg_f;
  const float* Whh = dir ? Whh_b : Whh_f;
  float* hbase = hencT + dir * 32768;
  unsigned* bc = ebar + dir * 64;

  float wge[2][16];
  #pragma unroll
  for (int p = 0; p < 2; ++p) {
    int jl = jj*2 + p;
    int j = (jl>>2)*512 + hibase + (jl&3);
    #pragma unroll
    for (int sc = 0; sc < 4; ++sc)
      #pragma unroll
      for (int i = 0; i < 4; ++i)
        wge[p][sc*4+i] = Whh[(size_t)j*512 + sc*128 + i*32 + kk];
  }
  float c_reg = 0.f;
  const int kr = tid >> 1, bh = (tid & 1) * 16;

  for (int tt = 0; tt < 64; ++tt) {
    const int t = dir ? (63 - tt) : tt;
    const float* hc = hbase + (tt & 1) * 16384;
    float* hn = hbase + ((tt + 1) & 1) * 16384;

    float a0[32], a1[32];
    #pragma unroll
    for (int q = 0; q < 32; ++q) { a0[q] = 0.f; a1[q] = 0.f; }

    float4 rr0, rr1, rr2, rr3;
    {
      const float4* p = (const float4*)(hc + kr*32 + bh);
      rr0 = p[0]; rr1 = p[1]; rr2 = p[2]; rr3 = p[3];
      float* d = &S_lds[0][kr*36 + bh];
      *(float4*)d = rr0; *(float4*)(d+4) = rr1; *(float4*)(d+8) = rr2; *(float4*)(d+12) = rr3;
    }
    __syncthreads();
    #pragma unroll
    for (int sc = 0; sc < 4; ++sc) {
      if (sc < 3) {
        const float4* p = (const float4*)(hc + (sc+1)*4096 + kr*32 + bh);
        rr0 = p[0]; rr1 = p[1]; rr2 = p[2]; rr3 = p[3];
      }
      const float* Sb = &S_lds[sc & 1][0];
      #pragma unroll
      for (int i = 0; i < 4; ++i) {
        const float* sp = Sb + (i*32 + kk)*36;
        float w0 = wge[0][sc*4+i], w1 = wge[1][sc*4+i];
        #pragma unroll
        for (int q = 0; q < 8; ++q) {
          float4 s4 = *(const float4*)(sp + q*4);
          a0[q*4+0] += w0*s4.x; a0[q*4+1] += w0*s4.y; a0[q*4+2] += w0*s4.z; a0[q*4+3] += w0*s4.w;
          a1[q*4+0] += w1*s4.x; a1[q*4+1] += w1*s4.y; a1[q*4+2] += w1*s4.z; a1[q*4+3] += w1*s4.w;
        }
      }
      if (sc < 3) {
        float* d = &S_lds[(sc+1) & 1][kr*36 + bh];
        *(float4*)d = rr0; *(float4*)(d+4) = rr1; *(float4*)(d+8) = rr2; *(float4*)(d+12) = rr3;
      }
      __syncthreads();
    }
    #pragma unroll
    for (int dd = 8; dd <= 32; dd <<= 1) {
      #pragma unroll
      for (int q = 0; q < 32; ++q) {
        a0[q] += __shfl_down(a0[q], dd, 64);
        a1[q] += __shfl_down(a1[q], dd, 64);
      }
    }
    if (lane < 8) {
      float* pw = &pacc[wv*512 + lane*64];
      #pragma unroll
      for (int q = 0; q < 32; ++q) { pw[q] = a0[q]; pw[32+q] = a1[q]; }
    }
    __syncthreads();
    #pragma unroll
    for (int r = 0; r < 2; ++r) {
      int o = tid + r*256;
      int jl = o >> 5, b = o & 31;
      int off = (jl>>1)*64 + (jl&1)*32 + b;
      float v = pacc[off] + pacc[512+off] + pacc[1024+off] + pacc[1536+off];
      v += xg[(size_t)(b*T + t)*2048 + (jl>>2)*512 + hibase + (jl&3)];
      g_lds[jl*32 + b] = v;
    }
    __syncthreads();
    if (tid < 128) {
      int hil = tid >> 5, b = tid & 31;
      float gi = g_lds[(0*4+hil)*32 + b];
      float gf = g_lds[(1*4+hil)*32 + b];
      float gg = g_lds[(2*4+hil)*32 + b];
      float go = g_lds[(3*4+hil)*32 + b];
      c_reg = sigm(gf)*c_reg + sigm(gi)*tanhf(gg);
      float h = sigm(go)*tanhf(c_reg);
      int hi = hibase + hil;
      hn[hi*32 + b] = h;
      outbuf[(size_t)(b*T + t)*H2 + dir*512 + hi] = h * (float)mask[b*T + t];
    }
    gbar(bc + tt, 128);
  }
}

// ---------------- persistent decoder: all weights register-resident --------------------
__global__ __launch_bounds__(256, 1) void decoder_persistent(
    const float* __restrict__ basep, const float* __restrict__ tagp,
    const float* __restrict__ dWhh,  const float* __restrict__ dWih,
    const float* __restrict__ Wout,  const float* __restrict__ bout,
    const float* __restrict__ projo, const float* __restrict__ outbuf,
    const int* __restrict__ mask,
    float* __restrict__ hT,          // [2][1024][32]
    float* __restrict__ ctxT,        // [2][1024][32]
    float* __restrict__ hrow,        // [32][1024]
    unsigned long long* __restrict__ argslot,
    unsigned* __restrict__ dbar,
    float* __restrict__ out)
{
  __shared__ float S_lds[2][128*36];
  __shared__ float pacc[2048];
  __shared__ float g_lds[512];
  __shared__ unsigned tag_lds[32];

  const int blk = blockIdx.x, tid = threadIdx.x;
  const int lane = tid & 63, wv = tid >> 6;
  const int hibase = blk * 4;
  const int jj = tid & 7, kk = tid >> 3;   // gates: j-pair, 32 k-groups
  const int vv = tid & 3, kq = tid >> 2;   // scores: v-pair, 64 k-groups
  const int vbase = blk * 8;
  const int kr = tid >> 1, bh = (tid & 1) * 16;

  // ---- preload weights into registers ----
  float wg[2][64];
  #pragma unroll
  for (int p = 0; p < 2; ++p) {
    int jl = jj*2 + p;
    int j = (jl>>2)*1024 + hibase + (jl&3);
    #pragma unroll
    for (int sc = 0; sc < 16; ++sc)
      #pragma unroll
      for (int i = 0; i < 4; ++i) {
        int k = sc*128 + i*32 + kk;
        wg[p][sc*4+i] = (k < 1024) ? dWhh[(size_t)j*1024 + k]
                                   : dWih[(size_t)j*2560 + 512 + (k - 1024)];
      }
  }
  float ws[2][32];
  #pragma unroll
  for (int p = 0; p < 2; ++p) {
    int v = vbase + vv*2 + p;
    #pragma unroll
    for (int sc = 0; sc < 16; ++sc)
      #pragma unroll
      for (int i = 0; i < 2; ++i)
        ws[p][sc*2+i] = Wout[(size_t)v*2048 + sc*128 + i*64 + kq];
  }

  float c_reg = 0.f;
  int bslot = 0;

  // ---- prologue: context0 = attend(last_output) ----
  if (blk < 32) {
    int b = blk;
    int len = -1;
    for (int i = 0; i < T; ++i) len += mask[b*T + i];
    attend_t(b, outbuf + (size_t)(b*T + len)*H2, ctxT, outbuf, projo, mask, pacc, tid);
  }
  gbar(dbar + bslot++, 256);

  for (int t = 0; t < T; ++t) {
    const int cur = t & 1, nxt = cur ^ 1;
    const float* hTc  = hT + cur*32768;
    float*       hTn  = hT + nxt*32768;
    const float* ctxc = ctxT + cur*32768;
    float*       ctxn = ctxT + nxt*32768;

    if (t > 0 && tid < 32) {
      unsigned long long s = argslot[((t+2)%3)*32 + tid];
      tag_lds[tid] = ~(unsigned)s;
    }

    // ===== phase 1: gates (K=2048: h | ctx) =====
    float a0[32], a1[32];
    #pragma unroll
    for (int q = 0; q < 32; ++q) { a0[q] = 0.f; a1[q] = 0.f; }
    {
      float4 rr0, rr1, rr2, rr3;
      {
        const float4* p = (const float4*)(hTc + kr*32 + bh);
        rr0 = p[0]; rr1 = p[1]; rr2 = p[2]; rr3 = p[3];
        float* d = &S_lds[0][kr*36 + bh];
        *(float4*)d = rr0; *(float4*)(d+4) = rr1; *(float4*)(d+8) = rr2; *(float4*)(d+12) = rr3;
      }
      __syncthreads();
      #pragma unroll
      for (int sc = 0; sc < 16; ++sc) {
        if (sc < 15) {
          const float* s0 = (sc+1 < 8) ? (hTc + (sc+1)*4096) : (ctxc + (sc+1-8)*4096);
          const float4* p = (const float4*)(s0 + kr*32 + bh);
          rr0 = p[0]; rr1 = p[1]; rr2 = p[2]; rr3 = p[3];
        }
        const float* Sb = &S_lds[sc & 1][0];
        #pragma unroll
        for (int i = 0; i < 4; ++i) {
          const float* sp = Sb + (i*32 + kk)*36;
          float w0 = wg[0][sc*4+i], w1 = wg[1][sc*4+i];
          #pragma unroll
          for (int q = 0; q < 8; ++q) {
            float4 s4 = *(const float4*)(sp + q*4);
            a0[q*4+0] += w0*s4.x; a0[q*4+1] += w0*s4.y; a0[q*4+2] += w0*s4.z; a0[q*4+3] += w0*s4.w;
            a1[q*4+0] += w1*s4.x; a1[q*4+1] += w1*s4.y; a1[q*4+2] += w1*s4.z; a1[q*4+3] += w1*s4.w;
          }
        }
        if (sc < 15) {
          float* d = &S_lds[(sc+1) & 1][kr*36 + bh];
          *(float4*)d = rr0; *(float4*)(d+4) = rr1; *(float4*)(d+8) = rr2; *(float4*)(d+12) = rr3;
        }
        __syncthreads();
      }
    }
    #pragma unroll
    for (int dd = 8; dd <= 32; dd <<= 1) {
      #pragma unroll
      for (int q = 0; q < 32; ++q) {
        a0[q] += __shfl_down(a0[q], dd, 64);
        a1[q] += __shfl_down(a1[q], dd, 64);
      }
    }
    if (lane < 8) {
      float* pw = &pacc[wv*512 + lane*64];
      #pragma unroll
      for (int q = 0; q < 32; ++q) { pw[q] = a0[q]; pw[32+q] = a1[q]; }
    }
    __syncthreads();
    #pragma unroll
    for (int r = 0; r < 2; ++r) {
      int o = tid + r*256;
      int jl = o >> 5, b = o & 31;
      int off = (jl>>1)*64 + (jl&1)*32 + b;
      float vsum = pacc[off] + pacc[512+off] + pacc[1024+off] + pacc[1536+off];
      int j = (jl>>2)*1024 + hibase + (jl&3);
      vsum += basep[(size_t)(b*T + t)*G4 + j];
      if (t > 0) vsum += tagp[(size_t)tag_lds[b]*G4 + j];
      g_lds[jl*32 + b] = vsum;
    }
    __syncthreads();
    if (tid < 128) {
      int hil = tid >> 5, b = tid & 31;
      float gi = g_lds[(0*4+hil)*32 + b];
      float gf = g_lds[(1*4+hil)*32 + b];
      float gg = g_lds[(2*4+hil)*32 + b];
      float go = g_lds[(3*4+hil)*32 + b];
      c_reg = sigm(gf)*c_reg + sigm(gi)*tanhf(gg);
      float h = sigm(go)*tanhf(c_reg);
      int hi = hibase + hil;
      hTn[hi*32 + b] = h;
      hrow[b*1024 + hi] = h;
    }
    gbar(dbar + bslot++, 256);

    // ===== phase 2: scores (K=2048: h_new | ctx_old) + argmax + attention =====
    #pragma unroll
    for (int q = 0; q < 32; ++q) { a0[q] = 0.f; a1[q] = 0.f; }
    {
      float4 rr0, rr1, rr2, rr3;
      {
        const float4* p = (const float4*)(hTn + kr*32 + bh);
        rr0 = p[0]; rr1 = p[1]; rr2 = p[2]; rr3 = p[3];
        float* d = &S_lds[0][kr*36 + bh];
        *(float4*)d = rr0; *(float4*)(d+4) = rr1; *(float4*)(d+8) = rr2; *(float4*)(d+12) = rr3;
      }
      __syncthreads();
      #pragma unroll
      for (int sc = 0; sc < 16; ++sc) {
        if (sc < 15) {
          const float* s0 = (sc+1 < 8) ? (hTn + (sc+1)*4096) : (ctxc + (sc+1-8)*4096);
          const float4* p = (const float4*)(s0 + kr*32 + bh);
          rr0 = p[0]; rr1 = p[1]; rr2 = p[2]; rr3 = p[3];
        }
        const float* Sb = &S_lds[sc & 1][0];
        #pragma unroll
        for (int i = 0; i < 2; ++i) {
          const float* sp = Sb + (i*64 + kq)*36;
          float w0 = ws[0][sc*2+i], w1 = ws[1][sc*2+i];
          #pragma unroll
          for (int q = 0; q < 8; ++q) {
            float4 s4 = *(const float4*)(sp + q*4);
            a0[q*4+0] += w0*s4.x; a0[q*4+1] += w0*s4.y; a0[q*4+2] += w0*s4.z; a0[q*4+3] += w0*s4.w;
            a1[q*4+0] += w1*s4.x; a1[q*4+1] += w1*s4.y; a1[q*4+2] += w1*s4.z; a1[q*4+3] += w1*s4.w;
          }
        }
        if (sc < 15) {
          float* d = &S_lds[(sc+1) & 1][kr*36 + bh];
          *(float4*)d = rr0; *(float4*)(d+4) = rr1; *(float4*)(d+8) = rr2; *(float4*)(d+12) = rr3;
        }
        __syncthreads();
      }
    }
    #pragma unroll
    for (int dd = 4; dd <= 32; dd <<= 1) {
      #pragma unroll
      for (int q = 0; q < 32; ++q) {
        a0[q] += __shfl_down(a0[q], dd, 64);
        a1[q] += __shfl_down(a1[q], dd, 64);
      }
    }
    if (lane < 4) {
      float* pw = &pacc[wv*256 + lane*64];
      #pragma unroll
      for (int q = 0; q < 32; ++q) { pw[q] = a0[q]; pw[32+q] = a1[q]; }
    }
    __syncthreads();
    {
      int vl = tid & 7, b = tid >> 3;
      int off = (vl>>1)*64 + (vl&1)*32 + b;
      float s = pacc[off] + pacc[256+off] + pacc[512+off] + pacc[768+off];
      s += bout[vbase + vl];
      out[(size_t)(b*T + t)*V + vbase + vl] = s;
      g_lds[vl*32 + b] = s;
    }
    __syncthreads();
    if (tid < 32) {
      int b = tid;
      float best = g_lds[b]; int bi = 0;
      #pragma unroll
      for (int vl = 1; vl < 8; ++vl) {
        float s = g_lds[vl*32 + b];
        if (s > best) { best = s; bi = vl; }
      }
      unsigned long long e = ((unsigned long long)fenc(best) << 32)
                           | (unsigned long long)(unsigned)(~(unsigned)(vbase + bi));
      atomicMax(&argslot[(t%3)*32 + b], e);
    } else if (blk == 0 && tid >= 32 && tid < 64) {
      argslot[((t+1)%3)*32 + (tid - 32)] = 0ull;
    }
    if (blk < 32) {
      __syncthreads();
      attend_t(blk, hrow + blk*1024, ctxn, outbuf, projo, mask, pacc, tid);
    }
    gbar(dbar + bslot++, 256);
  }
}

// ---------------- host launch ----------------
extern "C" void kernel_launch(void* const* d_in, const int* in_sizes, int n_in,
                              void* d_out, int out_size, void* d_ws, size_t ws_size,
                              hipStream_t stream)
{
  (void)in_sizes; (void)n_in; (void)out_size; (void)ws_size;
  const float* emb    = (const float*)d_in[0];
  const int*   mask   = (const int*)d_in[1];
  const float* Wih_f  = (const float*)d_in[2];
  const float* Whh_f  = (const float*)d_in[3];
  const float* bih_f  = (const float*)d_in[4];
  const float* bhh_f  = (const float*)d_in[5];
  const float* Wih_b  = (const float*)d_in[6];
  const float* Whh_b  = (const float*)d_in[7];
  const float* bih_b  = (const float*)d_in[8];
  const float* bhh_b  = (const float*)d_in[9];
  const float* attnW  = (const float*)d_in[10];
  const float* tagemb = (const float*)d_in[12];
  const float* dWih   = (const float*)d_in[13];
  const float* dWhh   = (const float*)d_in[14];
  const float* dbih   = (const float*)d_in[15];
  const float* dbhh   = (const float*)d_in[16];
  const float* Wout   = (const float*)d_in[17];
  const float* bout   = (const float*)d_in[18];
  float* out = (float*)d_out;

  float* ws = (float*)d_ws;
  float* xg_f   = ws + 0;          // 4194304
  float* xg_b   = ws + 4194304;    // 4194304
  float* outbuf = ws + 8388608;    // 2097152
  float* projo  = ws + 10485760;   // 2097152
  float* basep  = ws + 12582912;   // 8388608
  float* tagp   = ws + 20971520;   // 8388608
  float* hT     = ws + 29360128;   // 65536  [2][1024][32]
  float* ctxT   = ws + 29425664;   // 65536  [2][1024][32]
  float* hrow   = ws + 29491200;   // 32768
  float* hencT  = ws + 29523968;   // 65536  [2][2][512][32]
  unsigned long long* argslot = (unsigned long long*)(ws + 29589504);  // 96 u64
  unsigned* dbar = (unsigned*)(ws + 29589696);   // 512
  unsigned* ebar = (unsigned*)(ws + 29590208);   // 128
  // end: 29590336 floats

  // zero all persistent-kernel state every call (graph-replay deterministic)
  hipMemsetAsync((void*)(ws + 29360128), 0, (size_t)(29590336 - 29360128) * sizeof(float), stream);

  // xg = emb @ Wih^T + bih + bhh   (M=2048, N=2048, K=512)
  gemm_nt<<<dim3(32, 16), 256, 0, stream>>>(emb, 512, Wih_f, 512, xg_f, 2048, bih_f, bhh_f, 512);
  gemm_nt<<<dim3(32, 16), 256, 0, stream>>>(emb, 512, Wih_b, 512, xg_b, 2048, bih_b, bhh_b, 512);
  // tagp = tag_embed @ dec_Wih[:, :512]^T   (M=2048, N=4096, K=512)
  gemm_nt<<<dim3(64, 16), 256, 0, stream>>>(tagemb, 512, dWih, DEC_IN, tagp, G4, nullptr, nullptr, 512);
  // encoder scan (persistent, register-resident Whh)
  encoder_persistent<<<256, 256, 0, stream>>>(xg_f, xg_b, Whh_f, Whh_b, mask, hencT, outbuf, ebar);
  // projo[bt,d] = sum_e attn_W[d,e]*output[bt,e]   (M=2048, N=1024, K=1024)
  gemm_nt<<<dim3(16, 16), 256, 0, stream>>>(outbuf, H2, attnW, H2, projo, H2, nullptr, nullptr, H2);
  // basep = aligned @ dec_Wih[:,1536:]^T + dbih + dbhh   (M=2048, N=4096, K=1024)
  gemm_nt<<<dim3(64, 16), 256, 0, stream>>>(outbuf, H2, dWih + 1536, DEC_IN, basep, G4, dbih, dbhh, H2);
  // persistent decoder (weights in registers)
  decoder_persistent<<<256, 256, 0, stream>>>(basep, tagp, dWhh, dWih, Wout, bout,
                                              projo, outbuf, mask, hT, ctxT, hrow,
                                              argslot, dbar, out);
}

// Round 3
// 8263.329 us; speedup vs baseline: 3.4157x; 1.3442x over previous
//
#include <hip/hip_runtime.h>

#define B   32
#define T   64
#define D   512
#define H   512
#define H2  1024
#define G4  4096
#define V   2048
#define DEC_IN 2560

__device__ __forceinline__ float sigm(float x) { return 1.f / (1.f + expf(-x)); }

__device__ __forceinline__ unsigned fenc(float f) {
  unsigned u = __float_as_uint(f);
  return (u & 0x80000000u) ? ~u : (u | 0x80000000u);
}

// device-scope grid barrier; relaxed polling + one acquire at exit.
__device__ __forceinline__ void gbar(unsigned* ctr, unsigned target) {
  __syncthreads();
  if (threadIdx.x == 0) {
    __hip_atomic_fetch_add(ctr, 1u, __ATOMIC_ACQ_REL, __HIP_MEMORY_SCOPE_AGENT);
    while (__hip_atomic_load(ctr, __ATOMIC_RELAXED, __HIP_MEMORY_SCOPE_AGENT) < target)
      __builtin_amdgcn_s_sleep(2);
    (void)__hip_atomic_load(ctr, __ATOMIC_ACQUIRE, __HIP_MEMORY_SCOPE_AGENT);
  }
  __syncthreads();
}

// ---------------- generic fp32 GEMM:  C[m,n] = sum_k A[m,k]*W[n,k] + bias0[n] + bias1[n]
__global__ __launch_bounds__(256) void gemm_nt(
    const float* __restrict__ A, int lda,
    const float* __restrict__ W, int ldw,
    float* __restrict__ C, int ldc,
    const float* __restrict__ bias0, const float* __restrict__ bias1,
    int K)
{
  __shared__ float As[16][132];
  __shared__ float Ws[16][68];
  const int tid = threadIdx.x;
  const int nb = blockIdx.x * 64;
  const int mb = blockIdx.y * 128;
  const int tx = tid & 15;
  const int ty = tid >> 4;
  float acc[8][4] = {};

  const int am = tid >> 1, ak = (tid & 1) * 8;
  const int wn = tid >> 2, wk = (tid & 3) * 4;
  const float* aptr = A + (size_t)(mb + am) * lda + ak;
  const float* wptr = W + (size_t)(nb + wn) * ldw + wk;

  for (int k0 = 0; k0 < K; k0 += 16) {
    float4 u = *(const float4*)(aptr + k0);
    float4 v = *(const float4*)(aptr + k0 + 4);
    float4 w = *(const float4*)(wptr + k0);
    As[ak+0][am] = u.x; As[ak+1][am] = u.y; As[ak+2][am] = u.z; As[ak+3][am] = u.w;
    As[ak+4][am] = v.x; As[ak+5][am] = v.y; As[ak+6][am] = v.z; As[ak+7][am] = v.w;
    Ws[wk+0][wn] = w.x; Ws[wk+1][wn] = w.y; Ws[wk+2][wn] = w.z; Ws[wk+3][wn] = w.w;
    __syncthreads();
    #pragma unroll
    for (int k = 0; k < 16; ++k) {
      float4 a0 = *(const float4*)&As[k][ty*8];
      float4 a1 = *(const float4*)&As[k][ty*8+4];
      float4 wv = *(const float4*)&Ws[k][tx*4];
      float av[8] = {a0.x,a0.y,a0.z,a0.w,a1.x,a1.y,a1.z,a1.w};
      #pragma unroll
      for (int i = 0; i < 8; ++i) {
        acc[i][0] += av[i]*wv.x; acc[i][1] += av[i]*wv.y;
        acc[i][2] += av[i]*wv.z; acc[i][3] += av[i]*wv.w;
      }
    }
    __syncthreads();
  }
  float b4[4];
  #pragma unroll
  for (int j = 0; j < 4; ++j) {
    float bv = 0.f;
    if (bias0) bv += bias0[nb + tx*4 + j];
    if (bias1) bv += bias1[nb + tx*4 + j];
    b4[j] = bv;
  }
  #pragma unroll
  for (int i = 0; i < 8; ++i) {
    float4 o;
    o.x = acc[i][0] + b4[0]; o.y = acc[i][1] + b4[1];
    o.z = acc[i][2] + b4[2]; o.w = acc[i][3] + b4[3];
    *(float4*)&C[(size_t)(mb + ty*8 + i) * ldc + nb + tx*4] = o;
  }
}

// ---------------- attention helper: block handles batch row b; writes ctx transposed ----
__device__ void attend_t(int b, const float* __restrict__ hvec, float* __restrict__ ctxdst,
                         const float* __restrict__ outbuf, const float* __restrict__ projo,
                         const int* __restrict__ mask, float* scratch, int tid)
{
  float* scp = scratch;        // 256
  float* scv = scratch + 256;  // 64
  const int tq = tid >> 2, dq = tid & 3;
  const float4* hv = (const float4*)(hvec + dq*256);
  const float4* pv = (const float4*)(projo + (size_t)(b*T + tq)*H2 + dq*256);
  float p = 0.f;
  #pragma unroll 8
  for (int k4 = 0; k4 < 64; ++k4) {
    float4 a = hv[k4], q = pv[k4];
    p += a.x*q.x + a.y*q.y + a.z*q.z + a.w*q.w;
  }
  scp[tid] = p;
  __syncthreads();
  if (tid < 64) scv[tid] = scp[tid*4] + scp[tid*4+1] + scp[tid*4+2] + scp[tid*4+3];
  __syncthreads();
  if (tid == 0) {
    float mx = scv[0];
    for (int i = 1; i < 64; ++i) mx = fmaxf(mx, scv[i]);
    float sum = 0.f;
    for (int i = 0; i < 64; ++i) { float e = expf(scv[i] - mx); scv[i] = e; sum += e; }
    float inv = 1.f / sum;
    for (int i = 0; i < 64; ++i) scv[i] *= inv * (float)mask[b*T + i];
  }
  __syncthreads();
  float a0 = 0, a1 = 0, a2 = 0, a3 = 0;
  #pragma unroll 8
  for (int tt = 0; tt < 64; ++tt) {
    float pp = scv[tt];
    float4 o4 = *(const float4*)(outbuf + (size_t)(b*T + tt)*H2 + tid*4);
    a0 += pp*o4.x; a1 += pp*o4.y; a2 += pp*o4.z; a3 += pp*o4.w;
  }
  int k0 = tid*4;
  ctxdst[(k0+0)*32 + b] = a0;
  ctxdst[(k0+1)*32 + b] = a1;
  ctxdst[(k0+2)*32 + b] = a2;
  ctxdst[(k0+3)*32 + b] = a3;
}

// ---------------- persistent encoder: weights in registers (32 floats/thread) ----------
__global__ __launch_bounds__(256, 1) void encoder_persistent(
    const float* __restrict__ xg_f, const float* __restrict__ xg_b,
    const float* __restrict__ Whh_f, const float* __restrict__ Whh_b,
    const int* __restrict__ mask,
    float* __restrict__ hencT,    // [dir][2][512][32]
    float* __restrict__ outbuf,
    unsigned* __restrict__ ebar)
{
  __shared__ float S_lds[2][128*36];
  __shared__ float pacc[2048];
  __shared__ float g_lds[512];
  const int blk = blockIdx.x, tid = threadIdx.x;
  const int lane = tid & 63, wv = tid >> 6;
  const int dir = blk >> 7, nd = blk & 127;
  const int hibase = nd * 4;
  const int jj = tid & 7, kk = tid >> 3;
  const float* xg  = dir ? xg_b : xg_f;
  const float* Whh = dir ? Whh_b : Whh_f;
  float* hbase = hencT + dir * 32768;
  unsigned* bc = ebar + dir * 64;

  float wge[2][16];
  #pragma unroll
  for (int p = 0; p < 2; ++p) {
    int jl = jj*2 + p;
    int j = (jl>>2)*512 + hibase + (jl&3);
    #pragma unroll
    for (int sc = 0; sc < 4; ++sc)
      #pragma unroll
      for (int i = 0; i < 4; ++i)
        wge[p][sc*4+i] = Whh[(size_t)j*512 + sc*128 + i*32 + kk];
  }
  float c_reg = 0.f;
  const int kr = tid >> 1, bh = (tid & 1) * 16;

  for (int tt = 0; tt < 64; ++tt) {
    const int t = dir ? (63 - tt) : tt;
    const float* hc = hbase + (tt & 1) * 16384;
    float* hn = hbase + ((tt + 1) & 1) * 16384;

    float a0[32], a1[32];
    #pragma unroll
    for (int q = 0; q < 32; ++q) { a0[q] = 0.f; a1[q] = 0.f; }

    float4 rr0, rr1, rr2, rr3;
    {
      const float4* p = (const float4*)(hc + kr*32 + bh);
      rr0 = p[0]; rr1 = p[1]; rr2 = p[2]; rr3 = p[3];
      float* d = &S_lds[0][kr*36 + bh];
      *(float4*)d = rr0; *(float4*)(d+4) = rr1; *(float4*)(d+8) = rr2; *(float4*)(d+12) = rr3;
    }
    __syncthreads();
    #pragma unroll
    for (int sc = 0; sc < 4; ++sc) {
      if (sc < 3) {
        const float4* p = (const float4*)(hc + (sc+1)*4096 + kr*32 + bh);
        rr0 = p[0]; rr1 = p[1]; rr2 = p[2]; rr3 = p[3];
      }
      const float* Sb = &S_lds[sc & 1][0];
      #pragma unroll
      for (int i = 0; i < 4; ++i) {
        const float* sp = Sb + (i*32 + kk)*36;
        float w0 = wge[0][sc*4+i], w1 = wge[1][sc*4+i];
        #pragma unroll
        for (int q = 0; q < 8; ++q) {
          float4 s4 = *(const float4*)(sp + q*4);
          a0[q*4+0] += w0*s4.x; a0[q*4+1] += w0*s4.y; a0[q*4+2] += w0*s4.z; a0[q*4+3] += w0*s4.w;
          a1[q*4+0] += w1*s4.x; a1[q*4+1] += w1*s4.y; a1[q*4+2] += w1*s4.z; a1[q*4+3] += w1*s4.w;
        }
      }
      if (sc < 3) {
        float* d = &S_lds[(sc+1) & 1][kr*36 + bh];
        *(float4*)d = rr0; *(float4*)(d+4) = rr1; *(float4*)(d+8) = rr2; *(float4*)(d+12) = rr3;
      }
      __syncthreads();
    }
    #pragma unroll
    for (int dd = 8; dd <= 32; dd <<= 1) {
      #pragma unroll
      for (int q = 0; q < 32; ++q) {
        a0[q] += __shfl_down(a0[q], dd, 64);
        a1[q] += __shfl_down(a1[q], dd, 64);
      }
    }
    if (lane < 8) {
      float* pw = &pacc[wv*512 + lane*64];
      #pragma unroll
      for (int q = 0; q < 32; ++q) { pw[q] = a0[q]; pw[32+q] = a1[q]; }
    }
    __syncthreads();
    #pragma unroll
    for (int r = 0; r < 2; ++r) {
      int o = tid + r*256;
      int jl = o >> 5, b = o & 31;
      int off = (jl>>1)*64 + (jl&1)*32 + b;
      float v = pacc[off] + pacc[512+off] + pacc[1024+off] + pacc[1536+off];
      v += xg[(size_t)(b*T + t)*2048 + (jl>>2)*512 + hibase + (jl&3)];
      g_lds[jl*32 + b] = v;
    }
    __syncthreads();
    if (tid < 128) {
      int hil = tid >> 5, b = tid & 31;
      float gi = g_lds[(0*4+hil)*32 + b];
      float gf = g_lds[(1*4+hil)*32 + b];
      float gg = g_lds[(2*4+hil)*32 + b];
      float go = g_lds[(3*4+hil)*32 + b];
      c_reg = sigm(gf)*c_reg + sigm(gi)*tanhf(gg);
      float h = sigm(go)*tanhf(c_reg);
      int hi = hibase + hil;
      hn[hi*32 + b] = h;
      outbuf[(size_t)(b*T + t)*H2 + dir*512 + hi] = h * (float)mask[b*T + t];
    }
    gbar(bc + tt, 128);
  }
}

// ---------------- persistent decoder: gates weights in LDS, scores weights in regs ------
// Dynamic LDS layout (floats):
//   Wg   [16][2052]  = 32832   (gates weights, pad 2052 -> 2-way-free bank pattern)
//   S2   [2][64][36] = 4608    (double-buffered state slice, stride 36)
//   pacc [2048]                (cross-wave reduction / attend scratch)
//   g_lds[512]
//   tag  [32]  (unsigned)
// total 40032 floats = 160128 B (<= 163840 HW limit, 1 block/CU)
__global__ __launch_bounds__(256, 1) void decoder_persistent(
    const float* __restrict__ basep, const float* __restrict__ tagp,
    const float* __restrict__ dWhh,  const float* __restrict__ dWih,
    const float* __restrict__ Wout,  const float* __restrict__ bout,
    const float* __restrict__ projo, const float* __restrict__ outbuf,
    const int* __restrict__ mask,
    float* __restrict__ hT,          // [2][1024][32]
    float* __restrict__ ctxT,        // [2][1024][32]
    float* __restrict__ hrow,        // [32][1024]
    unsigned long long* __restrict__ argslot,
    unsigned* __restrict__ dbar,
    float* __restrict__ out)
{
  extern __shared__ float dyn[];
  float* Wg    = dyn;                 // 32832
  float* S2    = dyn + 32832;         // 4608
  float* pacc  = dyn + 37440;         // 2048
  float* g_lds = dyn + 39488;         // 512
  unsigned* tag_lds = (unsigned*)(dyn + 40000); // 32

  const int blk = blockIdx.x, tid = threadIdx.x;
  const int lane = tid & 63, wv = tid >> 6;
  const int hibase = blk * 4;
  const int jj = tid & 7, kk = tid >> 3;   // gates mapping
  const int vv = tid & 3, kq = tid >> 2;   // scores mapping
  const int vbase = blk * 8;
  const int jl0 = jj*2, jl1 = jj*2 + 1;

  // ---- preload gates weights into LDS (once; rows jl=gate*4+hil -> j=(jl>>2)*1024+hibase+(jl&3))
  for (int jl = 0; jl < 16; ++jl) {
    int j = (jl>>2)*1024 + hibase + (jl&3);
    #pragma unroll
    for (int r = 0; r < 2; ++r) {
      int c = tid*4 + r*1024;
      float4 w;
      if (c < 1024) w = *(const float4*)(dWhh + (size_t)j*1024 + c);
      else          w = *(const float4*)(dWih + (size_t)j*2560 + 512 + (c - 1024));
      *(float4*)&Wg[jl*2052 + c] = w;
    }
  }
  // ---- scores weights in registers (64 floats/thread) ----
  float ws0[32], ws1[32];
  {
    int v0 = vbase + vv*2;
    #pragma unroll
    for (int sl = 0; sl < 32; ++sl) {
      ws0[sl] = Wout[(size_t)(v0+0)*2048 + sl*64 + kq];
      ws1[sl] = Wout[(size_t)(v0+1)*2048 + sl*64 + kq];
    }
  }

  float c_reg = 0.f;
  int bslot = 0;

  // ---- prologue: context0 = attend(last_output) ----
  if (blk < 32) {
    int b = blk;
    int len = -1;
    for (int i = 0; i < T; ++i) len += mask[b*T + i];
    attend_t(b, outbuf + (size_t)(b*T + len)*H2, ctxT, outbuf, projo, mask, pacc, tid);
  }
  gbar(dbar + bslot++, 256);

  const int sr = tid >> 2;          // staging row 0..63
  const int scol = (tid & 3) * 8;   // staging col {0,8,16,24}

  for (int t = 0; t < T; ++t) {
    const int cur = t & 1, nxt = cur ^ 1;
    const float* hTc  = hT + cur*32768;
    float*       hTn  = hT + nxt*32768;
    const float* ctxc = ctxT + cur*32768;
    float*       ctxn = ctxT + nxt*32768;

    if (t > 0 && tid < 32) {
      unsigned long long s = argslot[((t+2)%3)*32 + tid];
      tag_lds[tid] = ~(unsigned)s;
    }

    // ===== phase 1: gates (K=2048: h | ctx), weights from LDS =====
    float a0[32], a1[32];
    #pragma unroll
    for (int q = 0; q < 32; ++q) { a0[q] = 0.f; a1[q] = 0.f; }
    {
      // stage slice 0 (k rows 0..63 from hTc)
      const float* src = hTc + sr*32 + scol;
      *(float4*)&S2[sr*36 + scol]     = *(const float4*)src;
      *(float4*)&S2[sr*36 + scol + 4] = *(const float4*)(src + 4);
      __syncthreads();
      for (int sl = 0; sl < 32; ++sl) {
        const int cb = sl & 1, nb2 = cb ^ 1;
        if (sl < 31) {
          int kr = (sl+1)*64 + sr;
          const float* bsrc = (kr < 1024) ? (hTc + kr*32) : (ctxc + (kr-1024)*32);
          *(float4*)&S2[nb2*2304 + sr*36 + scol]     = *(const float4*)(bsrc + scol);
          *(float4*)&S2[nb2*2304 + sr*36 + scol + 4] = *(const float4*)(bsrc + scol + 4);
        }
        const float* Sb = &S2[cb*2304];
        #pragma unroll
        for (int i = 0; i < 2; ++i) {
          float w0 = Wg[jl0*2052 + sl*64 + i*32 + kk];
          float w1 = Wg[jl1*2052 + sl*64 + i*32 + kk];
          const float* sp = Sb + (i*32 + kk)*36;
          #pragma unroll
          for (int q = 0; q < 8; ++q) {
            float4 s4 = *(const float4*)(sp + q*4);
            a0[q*4+0] += w0*s4.x; a0[q*4+1] += w0*s4.y; a0[q*4+2] += w0*s4.z; a0[q*4+3] += w0*s4.w;
            a1[q*4+0] += w1*s4.x; a1[q*4+1] += w1*s4.y; a1[q*4+2] += w1*s4.z; a1[q*4+3] += w1*s4.w;
          }
        }
        __syncthreads();
      }
    }
    #pragma unroll
    for (int dd = 8; dd <= 32; dd <<= 1) {
      #pragma unroll
      for (int q = 0; q < 32; ++q) {
        a0[q] += __shfl_down(a0[q], dd, 64);
        a1[q] += __shfl_down(a1[q], dd, 64);
      }
    }
    if (lane < 8) {
      float* pw = &pacc[wv*512 + lane*64];
      #pragma unroll
      for (int q = 0; q < 32; ++q) { pw[q] = a0[q]; pw[32+q] = a1[q]; }
    }
    __syncthreads();
    #pragma unroll
    for (int r = 0; r < 2; ++r) {
      int o = tid + r*256;
      int jl = o >> 5, b = o & 31;
      int off = (jl>>1)*64 + (jl&1)*32 + b;
      float vsum = pacc[off] + pacc[512+off] + pacc[1024+off] + pacc[1536+off];
      int j = (jl>>2)*1024 + hibase + (jl&3);
      vsum += basep[(size_t)(b*T + t)*G4 + j];
      if (t > 0) vsum += tagp[(size_t)tag_lds[b]*G4 + j];
      g_lds[jl*32 + b] = vsum;
    }
    __syncthreads();
    if (tid < 128) {
      int hil = tid >> 5, b = tid & 31;
      float gi = g_lds[(0*4+hil)*32 + b];
      float gf = g_lds[(1*4+hil)*32 + b];
      float gg = g_lds[(2*4+hil)*32 + b];
      float go = g_lds[(3*4+hil)*32 + b];
      c_reg = sigm(gf)*c_reg + sigm(gi)*tanhf(gg);
      float h = sigm(go)*tanhf(c_reg);
      int hi = hibase + hil;
      hTn[hi*32 + b] = h;
      hrow[b*1024 + hi] = h;
    }
    gbar(dbar + bslot++, 256);

    // ===== phase 2: scores (K=2048: h_new | ctx_old), weights in regs =====
    #pragma unroll
    for (int q = 0; q < 32; ++q) { a0[q] = 0.f; a1[q] = 0.f; }
    {
      const float* src = hTn + sr*32 + scol;
      *(float4*)&S2[sr*36 + scol]     = *(const float4*)src;
      *(float4*)&S2[sr*36 + scol + 4] = *(const float4*)(src + 4);
      __syncthreads();
      #pragma unroll
      for (int sl = 0; sl < 32; ++sl) {
        const int cb = sl & 1, nb2 = cb ^ 1;
        if (sl < 31) {
          int kr = (sl+1)*64 + sr;
          const float* bsrc = (kr < 1024) ? (hTn + kr*32) : (ctxc + (kr-1024)*32);
          *(float4*)&S2[nb2*2304 + sr*36 + scol]     = *(const float4*)(bsrc + scol);
          *(float4*)&S2[nb2*2304 + sr*36 + scol + 4] = *(const float4*)(bsrc + scol + 4);
        }
        const float* sp = &S2[cb*2304] + kq*36;
        float w0 = ws0[sl], w1 = ws1[sl];
        #pragma unroll
        for (int q = 0; q < 8; ++q) {
          float4 s4 = *(const float4*)(sp + q*4);
          a0[q*4+0] += w0*s4.x; a0[q*4+1] += w0*s4.y; a0[q*4+2] += w0*s4.z; a0[q*4+3] += w0*s4.w;
          a1[q*4+0] += w1*s4.x; a1[q*4+1] += w1*s4.y; a1[q*4+2] += w1*s4.z; a1[q*4+3] += w1*s4.w;
        }
        __syncthreads();
      }
    }
    #pragma unroll
    for (int dd = 4; dd <= 32; dd <<= 1) {
      #pragma unroll
      for (int q = 0; q < 32; ++q) {
        a0[q] += __shfl_down(a0[q], dd, 64);
        a1[q] += __shfl_down(a1[q], dd, 64);
      }
    }
    if (lane < 4) {
      float* pw = &pacc[wv*256 + lane*64];
      #pragma unroll
      for (int q = 0; q < 32; ++q) { pw[q] = a0[q]; pw[32+q] = a1[q]; }
    }
    __syncthreads();
    {
      int vl = tid & 7, b = tid >> 3;
      int off = (vl>>1)*64 + (vl&1)*32 + b;
      float s = pacc[off] + pacc[256+off] + pacc[512+off] + pacc[768+off];
      s += bout[vbase + vl];
      out[(size_t)(b*T + t)*V + vbase + vl] = s;
      g_lds[vl*32 + b] = s;
    }
    __syncthreads();
    if (tid < 32) {
      int b = tid;
      float best = g_lds[b]; int bi = 0;
      #pragma unroll
      for (int vl = 1; vl < 8; ++vl) {
        float s = g_lds[vl*32 + b];
        if (s > best) { best = s; bi = vl; }
      }
      unsigned long long e = ((unsigned long long)fenc(best) << 32)
                           | (unsigned long long)(unsigned)(~(unsigned)(vbase + bi));
      atomicMax(&argslot[(t%3)*32 + b], e);
    } else if (blk == 0 && tid >= 32 && tid < 64) {
      argslot[((t+1)%3)*32 + (tid - 32)] = 0ull;
    }
    if (blk < 32) {
      __syncthreads();
      attend_t(blk, hrow + blk*1024, ctxn, outbuf, projo, mask, pacc, tid);
    }
    gbar(dbar + bslot++, 256);
  }
}

// ---------------- host launch ----------------
extern "C" void kernel_launch(void* const* d_in, const int* in_sizes, int n_in,
                              void* d_out, int out_size, void* d_ws, size_t ws_size,
                              hipStream_t stream)
{
  (void)in_sizes; (void)n_in; (void)out_size; (void)ws_size;
  const float* emb    = (const float*)d_in[0];
  const int*   mask   = (const int*)d_in[1];
  const float* Wih_f  = (const float*)d_in[2];
  const float* Whh_f  = (const float*)d_in[3];
  const float* bih_f  = (const float*)d_in[4];
  const float* bhh_f  = (const float*)d_in[5];
  const float* Wih_b  = (const float*)d_in[6];
  const float* Whh_b  = (const float*)d_in[7];
  const float* bih_b  = (const float*)d_in[8];
  const float* bhh_b  = (const float*)d_in[9];
  const float* attnW  = (const float*)d_in[10];
  const float* tagemb = (const float*)d_in[12];
  const float* dWih   = (const float*)d_in[13];
  const float* dWhh   = (const float*)d_in[14];
  const float* dbih   = (const float*)d_in[15];
  const float* dbhh   = (const float*)d_in[16];
  const float* Wout   = (const float*)d_in[17];
  const float* bout   = (const float*)d_in[18];
  float* out = (float*)d_out;

  float* ws = (float*)d_ws;
  float* xg_f   = ws + 0;          // 4194304
  float* xg_b   = ws + 4194304;    // 4194304
  float* outbuf = ws + 8388608;    // 2097152
  float* projo  = ws + 10485760;   // 2097152
  float* basep  = ws + 12582912;   // 8388608
  float* tagp   = ws + 20971520;   // 8388608
  float* hT     = ws + 29360128;   // 65536  [2][1024][32]
  float* ctxT   = ws + 29425664;   // 65536  [2][1024][32]
  float* hrow   = ws + 29491200;   // 32768
  float* hencT  = ws + 29523968;   // 65536  [2][2][512][32]
  unsigned long long* argslot = (unsigned long long*)(ws + 29589504);  // 96 u64
  unsigned* dbar = (unsigned*)(ws + 29589696);   // 512
  unsigned* ebar = (unsigned*)(ws + 29590208);   // 128
  // end: 29590336 floats

  // allow 160128 B dynamic LDS for the decoder (gfx950: 160 KiB/workgroup)
  (void)hipFuncSetAttribute((const void*)decoder_persistent,
                            hipFuncAttributeMaxDynamicSharedMemorySize, 160128);

  // zero all persistent-kernel state every call (graph-replay deterministic)
  hipMemsetAsync((void*)(ws + 29360128), 0, (size_t)(29590336 - 29360128) * sizeof(float), stream);

  // xg = emb @ Wih^T + bih + bhh   (M=2048, N=2048, K=512)
  gemm_nt<<<dim3(32, 16), 256, 0, stream>>>(emb, 512, Wih_f, 512, xg_f, 2048, bih_f, bhh_f, 512);
  gemm_nt<<<dim3(32, 16), 256, 0, stream>>>(emb, 512, Wih_b, 512, xg_b, 2048, bih_b, bhh_b, 512);
  // tagp = tag_embed @ dec_Wih[:, :512]^T   (M=2048, N=4096, K=512)
  gemm_nt<<<dim3(64, 16), 256, 0, stream>>>(tagemb, 512, dWih, DEC_IN, tagp, G4, nullptr, nullptr, 512);
  // encoder scan (persistent, register-resident Whh)
  encoder_persistent<<<256, 256, 0, stream>>>(xg_f, xg_b, Whh_f, Whh_b, mask, hencT, outbuf, ebar);
  // projo[bt,d] = sum_e attn_W[d,e]*output[bt,e]   (M=2048, N=1024, K=1024)
  gemm_nt<<<dim3(16, 16), 256, 0, stream>>>(outbuf, H2, attnW, H2, projo, H2, nullptr, nullptr, H2);
  // basep = aligned @ dec_Wih[:,1536:]^T + dbih + dbhh   (M=2048, N=4096, K=1024)
  gemm_nt<<<dim3(64, 16), 256, 0, stream>>>(outbuf, H2, dWih + 1536, DEC_IN, basep, G4, dbih, dbhh, H2);
  // persistent decoder (gates weights -> LDS, scores weights -> regs)
  decoder_persistent<<<256, 256, 160128, stream>>>(basep, tagp, dWhh, dWih, Wout, bout,
                                                   projo, outbuf, mask, hT, ctxT, hrow,
                                                   argslot, dbar, out);
}